// Round 4
// baseline (316.509 us; speedup 1.0000x reference)
//
#include <hip/hip_runtime.h>

#define B_ 16
#define D_ 128
#define L_ 8192
#define M_ 128
#define NCHUNK 64
#define LT 128
#define SL 64
#define PHI_SCALE 0.08838834764831845f

typedef unsigned short ushort_t;
typedef ushort_t ushort8 __attribute__((ext_vector_type(8)));
typedef ushort_t ushort4v __attribute__((ext_vector_type(4)));
typedef float float4v __attribute__((ext_vector_type(4)));
typedef __bf16 bf16x8 __attribute__((ext_vector_type(8)));

__device__ __forceinline__ ushort_t f2bf(float f) {
    unsigned int u = __builtin_bit_cast(unsigned int, f);
    unsigned int r = u + 0x7FFFu + ((u >> 16) & 1u);   // RTNE
    return (ushort_t)(r >> 16);
}

__device__ __forceinline__ float bf2f(ushort_t u) {
    return __builtin_bit_cast(float, (unsigned int)u << 16);
}

__device__ __forceinline__ float4v mfma16(ushort8 a, ushort8 b, float4v c) {
    return __builtin_amdgcn_mfma_f32_16x16x32_bf16(
        __builtin_bit_cast(bf16x8, a), __builtin_bit_cast(bf16x8, b), c, 0, 0, 0);
}

// kernelF: features (D x M f32) -> global bf16 B-frag layout (2048 slots x 16B = 32KB).
// Slot bid: [kt 0..3][nt 0..7][lane64][j 0..7], B[k=d][n=m], lane=qb*16+cb ->
// k = kt*32+qb*8+j, m = nt*16+cb. L2-resident; read by every block of A and QC.
__global__ __launch_bounds__(256) void kernelF(const float* __restrict__ features,
                                               ushort_t* __restrict__ fglob) {
    int bid = blockIdx.x * 256 + threadIdx.x;   // 0..2047
    int cb = bid & 15, qb = (bid >> 4) & 3, nt = (bid >> 6) & 7, kt = bid >> 9;
    const float* fp = features + (kt * 32 + qb * 8) * M_ + nt * 16 + cb;
    ushort8 u;
#pragma unroll
    for (int j = 0; j < 8; ++j) u[j] = f2bf(fp[j * M_]);
    *(ushort8*)(fglob + bid * 8) = u;
}

// Kernel A: per (chunk,b): phi_k = relu(K^T F)*s ; kv_part[m][v] += phi^T V^T ; ksum partials.
// LDS = PA 16KB + VB 16KB = 32KB, bounds(256,3) -> 3 blocks/CU (12 waves). F-frags from global.
// kvp partials written as bf16 in kv-frag layout via LDS bounce (coalesced 16B stores).
__global__ __launch_bounds__(256, 3) void kernelA(const float* __restrict__ keys,
                                                  const float* __restrict__ values,
                                                  const ushort_t* __restrict__ fglob,
                                                  ushort_t* __restrict__ kvp,
                                                  float* __restrict__ ksum_p) {
    __shared__ ushort_t SB[16384];  // 32 KB: [0,8192)=PA, [8192,16384)=VB; reused for bounce
    ushort_t* PA = SB;
    ushort_t* VB = SB + 8192;

    const int tid = threadIdx.x;
    const int chunk = blockIdx.x, b = blockIdx.y;
    const int w = tid >> 6, lane = tid & 63;
    const int qa = lane >> 4, ra = lane & 15;
    const int l0 = chunk * LT;

    // per-it V addressing (invariant part)
    int v_off[4];
#pragma unroll
    for (int it = 0; it < 4; ++it) {
        int bid = tid + it * 256;
        int v  = ((bid >> 6) & 7) * 16 + (bid & 15);
        int lr = (bid >> 9) * 32 + ((bid >> 4) & 3) * 8;
        v_off[it] = (b * D_ + v) * L_ + lr;
    }
    const float* kcol = keys + (size_t)b * D_ * L_;

    float4v acc2[2][8];
    float   ksum_acc[8];
#pragma unroll
    for (int i = 0; i < 2; ++i)
#pragma unroll
        for (int nt = 0; nt < 8; ++nt) acc2[i][nt] = (float4v){0.f, 0.f, 0.f, 0.f};
#pragma unroll
    for (int nt = 0; nt < 8; ++nt) ksum_acc[nt] = 0.f;

#pragma unroll
    for (int s = 0; s < 2; ++s) {
        const int ls = l0 + s * SL;
        __syncthreads();  // prev GEMM2 done; PA/VB reusable

        // ---- batched V loads (raw f32)
        float4v vf0[4], vf1[4];
#pragma unroll
        for (int it = 0; it < 4; ++it) {
            const float* vp = values + v_off[it] + ls;
            vf0[it] = *(const float4v*)vp;
            vf1[it] = *(const float4v*)(vp + 4);
        }
        // ---- batched K loads (raw f32)
        float fk[4][8];
        const int l = ls + w * 16 + ra;
#pragma unroll
        for (int kt = 0; kt < 4; ++kt)
#pragma unroll
            for (int j = 0; j < 8; ++j)
                fk[kt][j] = kcol[(size_t)(kt * 32 + qa * 8 + j) * L_ + l];

        // ---- V -> LDS (B-frag layout B[k=l_rel][n=v])
#pragma unroll
        for (int it = 0; it < 4; ++it) {
            ushort8 u;
            u[0] = f2bf(vf0[it].x); u[1] = f2bf(vf0[it].y);
            u[2] = f2bf(vf0[it].z); u[3] = f2bf(vf0[it].w);
            u[4] = f2bf(vf1[it].x); u[5] = f2bf(vf1[it].y);
            u[6] = f2bf(vf1[it].z); u[7] = f2bf(vf1[it].w);
            *(ushort8*)(VB + (tid + it * 256) * 8) = u;
        }
        // ---- K convert
        ushort8 af[4];
#pragma unroll
        for (int kt = 0; kt < 4; ++kt) {
            ushort8 a;
#pragma unroll
            for (int j = 0; j < 8; ++j) a[j] = f2bf(fk[kt][j]);
            af[kt] = a;
        }

        // ---- GEMM1: phi(64 x 128) = K_sub^T @ F; F B-frags direct from global (L2)
        float4v acc1[8];
#pragma unroll
        for (int nt = 0; nt < 8; ++nt) acc1[nt] = (float4v){0.f, 0.f, 0.f, 0.f};
#pragma unroll
        for (int kt = 0; kt < 4; ++kt) {
            ushort8 fb[8];
#pragma unroll
            for (int nt = 0; nt < 8; ++nt)
                fb[nt] = *(const ushort8*)(fglob + ((kt * 8 + nt) * 64 + lane) * 8);
#pragma unroll
            for (int nt = 0; nt < 8; ++nt) acc1[nt] = mfma16(af[kt], fb[nt], acc1[nt]);
        }

        // ---- epilogue: relu*scale, ksum accumulate, phi^T -> PA (A-frag layout)
        {
            const int qc = qa, cc = ra;
            const int kt2 = w >> 1;
            const int qa2 = (w & 1) * 2 + (qc >> 1);
            const int jb  = (qc & 1) * 4;
#pragma unroll
            for (int nt = 0; nt < 8; ++nt) {
                float4v p = acc1[nt];
                p.x = fmaxf(p.x, 0.f) * PHI_SCALE;
                p.y = fmaxf(p.y, 0.f) * PHI_SCALE;
                p.z = fmaxf(p.z, 0.f) * PHI_SCALE;
                p.w = fmaxf(p.w, 0.f) * PHI_SCALE;
                ksum_acc[nt] += p.x + p.y + p.z + p.w;
                ushort4v u4 = {f2bf(p.x), f2bf(p.y), f2bf(p.z), f2bf(p.w)};
                *(ushort4v*)(PA + (((kt2 * 8 + nt) * 64 + qa2 * 16 + cc) * 8 + jb)) = u4;
            }
        }
        __syncthreads();  // PA + VB visible

        // ---- GEMM2: kv[m][v] += phi^T (128 x 64) @ V (64 x 128); wave w owns m [32w,32w+32)
#pragma unroll
        for (int kt2 = 0; kt2 < 2; ++kt2) {
            ushort8 a0 = *(const ushort8*)(PA + ((kt2 * 8 + 2 * w + 0) * 64 + lane) * 8);
            ushort8 a1 = *(const ushort8*)(PA + ((kt2 * 8 + 2 * w + 1) * 64 + lane) * 8);
#pragma unroll
            for (int nt = 0; nt < 8; ++nt) {
                ushort8 bb = *(const ushort8*)(VB + ((kt2 * 8 + nt) * 64 + lane) * 8);
                acc2[0][nt] = mfma16(a0, bb, acc2[0][nt]);
                acc2[1][nt] = mfma16(a1, bb, acc2[1][nt]);
            }
        }
    }

    // ---- bounce acc2 (C-frag) -> bf16 kv-frag layout -> coalesced global stores
    __syncthreads();  // all GEMM2 LDS reads done; SB reusable as scratch
    {
        const int qc = lane >> 4, cc = lane & 15;
#pragma unroll
        for (int mi = 0; mi < 2; ++mi)
#pragma unroll
            for (int nt = 0; nt < 8; ++nt) {
                float4v p = acc2[mi][nt];
                ushort4v u4 = {f2bf(p.x), f2bf(p.y), f2bf(p.z), f2bf(p.w)};
                int tile = (w * 2 + mi) * 8 + nt;
                *(ushort4v*)(SB + tile * 256 + (qc * 16 + cc) * 4) = u4;
            }
    }
    __syncthreads();
    {
        const int qb2 = lane >> 4, cb2 = lane & 15;
        ushort_t* kvpb = kvp + ((size_t)(b * NCHUNK + chunk)) * (M_ * D_);
#pragma unroll
        for (int nt = 0; nt < 8; ++nt) {
            int tile = (w * 2 + (qb2 >> 1)) * 8 + nt;  // kt = w for this wave's m-range
            ushort4v lo = *(const ushort4v*)(SB + tile * 256 + (((qb2 & 1) * 2 + 0) * 16 + cb2) * 4);
            ushort4v hi = *(const ushort4v*)(SB + tile * 256 + (((qb2 & 1) * 2 + 1) * 16 + cb2) * 4);
            ushort8 u;
            u[0] = lo[0]; u[1] = lo[1]; u[2] = lo[2]; u[3] = lo[3];
            u[4] = hi[0]; u[5] = hi[1]; u[6] = hi[2]; u[7] = hi[3];
            *(ushort8*)(kvpb + ((w * 8 + nt) * 64 + lane) * 8) = u;
        }
    }
    // ---- ksum partials
    float* ksb = ksum_p + ((size_t)((b * NCHUNK + chunk) * 4 + w)) * M_;
    const int qc = lane >> 4, cc = lane & 15;
#pragma unroll
    for (int nt = 0; nt < 8; ++nt) {
        float sv = ksum_acc[nt];
        sv += __shfl_xor(sv, 16);
        sv += __shfl_xor(sv, 32);
        if (qc == 0) ksb[nt * 16 + cc] = sv;
    }
}

// Kernel R: reduce 64 bf16 chunk-partials (frag layout, fully coalesced) -> kv_final bf16
// frag layout + ksum_final f32 [b][128]. 256 blocks kv + 8 blocks ksum.
__global__ __launch_bounds__(256) void kernelR(const ushort_t* __restrict__ kvp,
                                               const float* __restrict__ ksum_p,
                                               ushort_t* __restrict__ kv_final,
                                               float* __restrict__ ksum_final) {
    if (blockIdx.x < 256) {
        int t = blockIdx.x * 256 + threadIdx.x;   // 0..65535
        int b = t >> 12, rest = t & 4095;
        int bid = rest >> 1, half = rest & 1;
        const ushort_t* base = kvp + (((size_t)b * NCHUNK) * 2048 + bid) * 8 + half * 4;
        float s0 = 0.f, s1 = 0.f, s2 = 0.f, s3 = 0.f;
#pragma unroll 4
        for (int c = 0; c < NCHUNK; ++c) {
            ushort4v u = *(const ushort4v*)(base + (size_t)c * (M_ * D_));
            s0 += bf2f(u[0]); s1 += bf2f(u[1]); s2 += bf2f(u[2]); s3 += bf2f(u[3]);
        }
        ushort4v o = {f2bf(s0), f2bf(s1), f2bf(s2), f2bf(s3)};
        *(ushort4v*)(kv_final + ((size_t)b * 2048 + bid) * 8 + half * 4) = o;
    } else {
        int t2 = (blockIdx.x - 256) * 256 + threadIdx.x;  // 0..2047
        int b = t2 >> 7, m = t2 & 127;
        const float* p = ksum_p + (size_t)b * (NCHUNK * 4) * M_ + m;
        float sacc = 0.f;
#pragma unroll 8
        for (int cw = 0; cw < NCHUNK * 4; ++cw) sacc += p[cw * M_];
        ksum_final[t2] = sacc;
    }
}

// Kernel QC (fused): phi_q = relu(Q^T F)*s ; out = (phi_q @ kv)/(phi_q . ksum).
// F-frags and KV-frags direct from global (L2-resident); LDS = per-wave PQA 8KB only;
// ZERO barriers -> waves free-run. bounds(256,3) -> 3 blocks/CU (12 waves).
__global__ __launch_bounds__(256, 3) void kernelQC(const float* __restrict__ queries,
                                                   const ushort_t* __restrict__ fglob,
                                                   const ushort_t* __restrict__ kv_final,
                                                   const float* __restrict__ ksum_final,
                                                   float* __restrict__ out) {
    __shared__ ushort_t PQA[4096];   //  8 KB : phi_q A-frags, per-wave-private blocks

    const int tid = threadIdx.x;
    const int chunk = blockIdx.x, b = blockIdx.y;
    const int w = tid >> 6, lane = tid & 63;
    const int qa = lane >> 4, ra = lane & 15;
    const int qc = qa, cc = ra;

    const ushort_t* kvf = kv_final + (size_t)b * 2048 * 8;
    const float* qbase = queries + (size_t)b * D_ * L_;
    float ks[8];
#pragma unroll
    for (int nt = 0; nt < 8; ++nt) ks[nt] = ksum_final[b * M_ + nt * 16 + ra];

#pragma unroll
    for (int s = 0; s < 2; ++s) {
        const int ls = chunk * LT + s * SL;
        const int l = ls + w * 16 + ra;

        // ---- batched Q gather (raw f32), convert
        float fq[4][8];
#pragma unroll
        for (int kt = 0; kt < 4; ++kt)
#pragma unroll
            for (int j = 0; j < 8; ++j)
                fq[kt][j] = qbase[(size_t)(kt * 32 + qa * 8 + j) * L_ + l];
        ushort8 af[4];
#pragma unroll
        for (int kt = 0; kt < 4; ++kt) {
            ushort8 a;
#pragma unroll
            for (int j = 0; j < 8; ++j) a[j] = f2bf(fq[kt][j]);
            af[kt] = a;
        }

        // ---- GEMM1: phi_q(64 x 128) = Q_sub^T @ F; F B-frags direct from global
        float4v acc1[8];
#pragma unroll
        for (int nt = 0; nt < 8; ++nt) acc1[nt] = (float4v){0.f, 0.f, 0.f, 0.f};
#pragma unroll
        for (int kt = 0; kt < 4; ++kt) {
            ushort8 fb[8];
#pragma unroll
            for (int nt = 0; nt < 8; ++nt)
                fb[nt] = *(const ushort8*)(fglob + ((kt * 8 + nt) * 64 + lane) * 8);
#pragma unroll
            for (int nt = 0; nt < 8; ++nt) acc1[nt] = mfma16(af[kt], fb[nt], acc1[nt]);
        }

        // ---- relu*scale + f32 denominator dot (ksum in regs)
        float dp0 = 0.f, dp1 = 0.f, dp2 = 0.f, dp3 = 0.f;
#pragma unroll
        for (int nt = 0; nt < 8; ++nt) {
            float4v p = acc1[nt];
            p.x = fmaxf(p.x, 0.f) * PHI_SCALE;
            p.y = fmaxf(p.y, 0.f) * PHI_SCALE;
            p.z = fmaxf(p.z, 0.f) * PHI_SCALE;
            p.w = fmaxf(p.w, 0.f) * PHI_SCALE;
            dp0 += p.x * ks[nt]; dp1 += p.y * ks[nt];
            dp2 += p.z * ks[nt]; dp3 += p.w * ks[nt];
            acc1[nt] = p;
        }
#pragma unroll
        for (int off = 1; off < 16; off <<= 1) {
            dp0 += __shfl_xor(dp0, off);
            dp1 += __shfl_xor(dp1, off);
            dp2 += __shfl_xor(dp2, off);
            dp3 += __shfl_xor(dp3, off);
        }
        float i0 = 1.f / dp0, i1 = 1.f / dp1, i2 = 1.f / dp2, i3 = 1.f / dp3;

        // ---- GEMM2 in two m-halves via per-wave PQA; KV B-frags direct from global
        float4v acc[8];
#pragma unroll
        for (int nt = 0; nt < 8; ++nt) acc[nt] = (float4v){0.f, 0.f, 0.f, 0.f};
#pragma unroll
        for (int h = 0; h < 2; ++h) {
#pragma unroll
            for (int nt = 4 * h; nt < 4 * h + 4; ++nt) {
                float4v p = acc1[nt];
                int baseu = ((((nt >> 1) & 1) * 4 + w) * 64 +
                             ((nt & 1) * 2 + (cc >> 3)) * 16 + qc * 4) * 8 + (cc & 7);
                PQA[baseu +  0] = f2bf(p.x);
                PQA[baseu +  8] = f2bf(p.y);
                PQA[baseu + 16] = f2bf(p.z);
                PQA[baseu + 24] = f2bf(p.w);
            }
#pragma unroll
            for (int kt = 2 * h; kt < 2 * h + 2; ++kt) {
                ushort8 a = *(const ushort8*)(PQA + (((kt & 1) * 4 + w) * 64 + lane) * 8);
                ushort8 kb[8];
#pragma unroll
                for (int nt2 = 0; nt2 < 8; ++nt2)
                    kb[nt2] = *(const ushort8*)(kvf + ((kt * 8 + nt2) * 64 + lane) * 8);
#pragma unroll
                for (int nt2 = 0; nt2 < 8; ++nt2)
                    acc[nt2] = mfma16(a, kb[nt2], acc[nt2]);
            }
        }

        // ---- scale by 1/denom and store
        const int lbase = ls + w * 16 + qc * 4;
#pragma unroll
        for (int nt = 0; nt < 8; ++nt) {
            float4v o = acc[nt];
            o.x *= i0; o.y *= i1; o.z *= i2; o.w *= i3;
            *(float4v*)(out + ((size_t)(b * D_ + nt * 16 + cc)) * L_ + lbase) = o;
        }
    }
}

extern "C" void kernel_launch(void* const* d_in, const int* in_sizes, int n_in,
                              void* d_out, int out_size, void* d_ws, size_t ws_size,
                              hipStream_t stream) {
    (void)in_sizes; (void)n_in; (void)out_size; (void)ws_size;
    const float* keys     = (const float*)d_in[0];
    const float* values   = (const float*)d_in[1];
    const float* queries  = (const float*)d_in[2];
    const float* features = (const float*)d_in[3];
    float* out = (float*)d_out;

    // workspace partition (total ~36.2 MB; harness provisions >= 51 MB per round 0)
    char* ws = (char*)d_ws;
    ushort_t* kvp        = (ushort_t*)ws;                     // 16*64*128*128*2 = 33,554,432
    float*    ksum_p     = (float*)(ws + 33554432);           // 16*64*4*128*4   =  2,097,152
    ushort_t* kv_final   = (ushort_t*)(ws + 35651584);        // 16*2048*8*2     =    524,288
    float*    ksum_final = (float*)(ws + 36175872);           // 16*128*4        =      8,192
    ushort_t* fglob      = (ushort_t*)(ws + 36184064);        // 2048*8*2        =     32,768

    dim3 grid(NCHUNK, B_);
    kernelF<<<8, 256, 0, stream>>>(features, fglob);
    kernelA<<<grid, 256, 0, stream>>>(keys, values, fglob, kvp, ksum_p);
    kernelR<<<264, 256, 0, stream>>>(kvp, ksum_p, kv_final, ksum_final);
    kernelQC<<<grid, 256, 0, stream>>>(queries, fglob, kv_final, ksum_final, out);
}